// Round 7
// baseline (378.430 us; speedup 1.0000x reference)
//
#include <hip/hip_runtime.h>
#include <hip/hip_bf16.h>

// GCN encoder: z = relu(A @ relu(A @ (x@W1) + b1) @ W2 + b2)
// R7: register-prefetch software pipeline in both GEMMs (loads for tile k+1
// issued before tile k's compute phase -- R6 showed 0 conflicts but gemm1
// still 61us at MfmaUtil 7.8%: pure VMEM-latency exposure at 3 waves/SIMD,
// 8 k-iters). Packed v_cvt via __float22bfloat162_rn for the fused fp32->bf16
// A-staging. XOR-swizzled LDS kept (conflicts stay 0).

typedef __attribute__((ext_vector_type(8))) short bf16x8;
typedef __attribute__((ext_vector_type(4))) float f32x4;

#define NN 50000
#define NE 800000
#define NF 512
#define NH 256
#define NL 128
#define NB ((NN + 255) / 256)

static __device__ __forceinline__ unsigned short f2bf(float f) {
  union { float f; unsigned int u; } v; v.f = f;
  unsigned int r = v.u + 0x7fffu + ((v.u >> 16) & 1u);   // RNE
  return (unsigned short)(r >> 16);
}
static __device__ __forceinline__ float bf2f(unsigned short u) {
  union { unsigned int u; float f; } v; v.u = (unsigned int)u << 16;
  return v.f;
}
static __device__ __forceinline__ unsigned int pk2bf(float a, float b) {
  __hip_bfloat162 h = __float22bfloat162_rn(make_float2(a, b));  // v_cvt_pk_bf16_f32
  union { __hip_bfloat162 h; unsigned int u; } v; v.h = h;
  return v.u;
}

// ---------------- CSR build ----------------
extern "C" __global__ void k_hist(const int* __restrict__ rows, int* __restrict__ counts, int n) {
  int i = blockIdx.x * 256 + threadIdx.x;
  if (i < n) atomicAdd(&counts[rows[i]], 1);
}

extern "C" __global__ __launch_bounds__(256) void k_blocksum(
    const int* __restrict__ counts, int* __restrict__ bsum, int n) {
  __shared__ int s[256];
  int t = threadIdx.x;
  int i = blockIdx.x * 256 + t;
  s[t] = (i < n) ? counts[i] : 0;
  __syncthreads();
  for (int off = 128; off > 0; off >>= 1) {
    if (t < off) s[t] += s[t + off];
    __syncthreads();
  }
  if (t == 0) bsum[blockIdx.x] = s[0];
}

extern "C" __global__ __launch_bounds__(256) void k_scansums(
    const int* __restrict__ bsum, int* __restrict__ bpre, int* __restrict__ rp, int nb, int n) {
  __shared__ int s[256];
  int t = threadIdx.x;
  int v = (t < nb) ? bsum[t] : 0;
  s[t] = v;
  __syncthreads();
  for (int off = 1; off < 256; off <<= 1) {
    int u = (t >= off) ? s[t - off] : 0;
    __syncthreads();
    s[t] += u;
    __syncthreads();
  }
  if (t < nb) bpre[t] = s[t] - v;
  if (t == 255) rp[n] = s[255];
}

extern "C" __global__ __launch_bounds__(256) void k_scanfin(
    const int* __restrict__ counts, const int* __restrict__ bpre,
    int* __restrict__ rp, int* __restrict__ cur, int n) {
  __shared__ int s[256];
  int t = threadIdx.x;
  int i = blockIdx.x * 256 + t;
  int c = (i < n) ? counts[i] : 0;
  s[t] = c;
  __syncthreads();
  for (int off = 1; off < 256; off <<= 1) {
    int u = (t >= off) ? s[t - off] : 0;
    __syncthreads();
    s[t] += u;
    __syncthreads();
  }
  if (i < n) {
    int e = bpre[blockIdx.x] + s[t] - c;
    rp[i] = e;
    cur[i] = e;
  }
}

extern "C" __global__ void k_scatter(const int* __restrict__ rows, const int* __restrict__ cols,
    const float* __restrict__ vals, int* __restrict__ cur, int2* __restrict__ ep, int n) {
  int i = blockIdx.x * 256 + threadIdx.x;
  if (i < n) {
    int p = atomicAdd(&cur[rows[i]], 1);
    int2 e; e.x = cols[i]; e.y = __float_as_int(vals[i]);
    ep[p] = e;
  }
}

// ---------------- weight transpose-cast: W [K][N] fp32 -> WT [N][K] bf16 ----------------
extern "C" __global__ void k_transcast(const float* __restrict__ w, unsigned short* __restrict__ wt,
                                       int K, int N) {
  int k = blockIdx.x; int n = threadIdx.x;
  wt[(size_t)n * K + k] = f2bf(w[(size_t)k * N + n]);
}

// ---------------- GEMM1: C[NN][256] = x[NN][512](fp32) * W1T[256][512]^T, bf16 out ----------------
// BM=128 BN=128 BK=64, register-prefetch pipeline, swizzled LDS.
extern "C" __global__ __launch_bounds__(256, 3) void k_gemm1(
    const float* __restrict__ A, const unsigned short* __restrict__ BT,
    unsigned short* __restrict__ C) {
  __shared__ __align__(16) unsigned short sA[128 * 64];
  __shared__ __align__(16) unsigned short sB[128 * 64];
  int tid = threadIdx.x;
  int lane = tid & 63, wid = tid >> 6;
  int wm = (wid >> 1) * 64, wn = (wid & 1) * 64;
  int bm = blockIdx.x * 128, bn = blockIdx.y * 128;
  int l15 = lane & 15, lq = lane >> 4;
  int swzbase = l15 & 7;
  f32x4 acc[4][4];
#pragma unroll
  for (int i = 0; i < 4; ++i)
#pragma unroll
    for (int j = 0; j < 4; ++j) acc[i][j] = (f32x4){0.f, 0.f, 0.f, 0.f};

  // per-thread staging coords (4 units each for A and B)
  int arow[4], acu[4];
  const float* aptr[4];
  const unsigned short* bptr[4];
  unsigned int asw[4], bsw[4];
#pragma unroll
  for (int j = 0; j < 4; ++j) {
    int u = tid + 256 * j;
    int row = u >> 3, cu = u & 7;
    arow[j] = row; acu[j] = cu;
    int ga = bm + row; if (ga >= NN) ga = NN - 1;
    aptr[j] = A + (size_t)ga * NF + cu * 8;
    bptr[j] = BT + (size_t)(bn + row) * NF + cu * 8;
    asw[j] = row * 64 + (cu ^ (row & 7)) * 8;
    bsw[j] = asw[j];
  }

  float4 pa[4][2];
  bf16x8 pb[4];
  // preload k=0
#pragma unroll
  for (int j = 0; j < 4; ++j) {
    pa[j][0] = *(const float4*)(aptr[j]);
    pa[j][1] = *(const float4*)(aptr[j] + 4);
    pb[j] = *(const bf16x8*)(bptr[j]);
  }

  for (int k0 = 0; k0 < NF; k0 += 64) {
    // write staged tile k into LDS
#pragma unroll
    for (int j = 0; j < 4; ++j) {
      uint4 o;
      o.x = pk2bf(pa[j][0].x, pa[j][0].y);
      o.y = pk2bf(pa[j][0].z, pa[j][0].w);
      o.z = pk2bf(pa[j][1].x, pa[j][1].y);
      o.w = pk2bf(pa[j][1].z, pa[j][1].w);
      *(uint4*)(&sA[asw[j]]) = o;
      *(bf16x8*)(&sB[bsw[j]]) = pb[j];
    }
    __syncthreads();
    // issue prefetch for k+1 (latency overlaps compute below)
    if (k0 + 64 < NF) {
#pragma unroll
      for (int j = 0; j < 4; ++j) {
        pa[j][0] = *(const float4*)(aptr[j] + k0 + 64);
        pa[j][1] = *(const float4*)(aptr[j] + k0 + 64 + 4);
        pb[j] = *(const bf16x8*)(bptr[j] + k0 + 64);
      }
    }
    // compute
#pragma unroll
    for (int ks = 0; ks < 64; ks += 32) {
      bf16x8 af[4], bfr[4];
#pragma unroll
      for (int t = 0; t < 4; ++t) {
        int sz = (((ks >> 3) + lq) ^ swzbase) * 8;
        af[t]  = *(const bf16x8*)(&sA[(wm + t * 16 + l15) * 64 + sz]);
        bfr[t] = *(const bf16x8*)(&sB[(wn + t * 16 + l15) * 64 + sz]);
      }
#pragma unroll
      for (int mt = 0; mt < 4; ++mt)
#pragma unroll
        for (int nt = 0; nt < 4; ++nt)
          acc[mt][nt] = __builtin_amdgcn_mfma_f32_16x16x32_bf16(af[mt], bfr[nt], acc[mt][nt], 0, 0, 0);
    }
    __syncthreads();
  }
#pragma unroll
  for (int mt = 0; mt < 4; ++mt) {
#pragma unroll
    for (int r = 0; r < 4; ++r) {
      int gr = bm + wm + mt * 16 + lq * 4 + r;
      if (gr < NN) {
#pragma unroll
        for (int nt = 0; nt < 4; ++nt) {
          int gc = bn + wn + nt * 16 + l15;
          C[(size_t)gr * NH + gc] = f2bf(acc[mt][nt][r]);
        }
      }
    }
  }
}

// ---------------- GEMM2: C[NN][128] = h[NN][256](bf16) * W2T[128][256]^T, bf16 out ----------------
// BM=64 BN=128 BK=64, register-prefetch pipeline, swizzled LDS.
extern "C" __global__ __launch_bounds__(256) void k_gemm2(
    const unsigned short* __restrict__ A, const unsigned short* __restrict__ BT,
    unsigned short* __restrict__ C) {
  __shared__ __align__(16) unsigned short sA[64 * 64];
  __shared__ __align__(16) unsigned short sB[128 * 64];
  int tid = threadIdx.x;
  int lane = tid & 63, wid = tid >> 6;
  int wm = (wid >> 1) * 32, wn = (wid & 1) * 64;
  int bm = blockIdx.x * 64;
  int l15 = lane & 15, lq = lane >> 4;
  int swzbase = l15 & 7;
  f32x4 acc[2][4];
#pragma unroll
  for (int i = 0; i < 2; ++i)
#pragma unroll
    for (int j = 0; j < 4; ++j) acc[i][j] = (f32x4){0.f, 0.f, 0.f, 0.f};

  const unsigned short* aptr[2];
  const unsigned short* bptr[4];
  unsigned int asw[2], bsw[4];
#pragma unroll
  for (int j = 0; j < 2; ++j) {
    int u = tid + 256 * j;
    int row = u >> 3, cu = u & 7;
    int ga = bm + row; if (ga >= NN) ga = NN - 1;
    aptr[j] = A + (size_t)ga * NH + cu * 8;
    asw[j] = row * 64 + (cu ^ (row & 7)) * 8;
  }
#pragma unroll
  for (int j = 0; j < 4; ++j) {
    int u = tid + 256 * j;
    int row = u >> 3, cu = u & 7;
    bptr[j] = BT + (size_t)row * NH + cu * 8;
    bsw[j] = row * 64 + (cu ^ (row & 7)) * 8;
  }

  bf16x8 pA[2], pB[4];
#pragma unroll
  for (int j = 0; j < 2; ++j) pA[j] = *(const bf16x8*)(aptr[j]);
#pragma unroll
  for (int j = 0; j < 4; ++j) pB[j] = *(const bf16x8*)(bptr[j]);

  for (int k0 = 0; k0 < NH; k0 += 64) {
#pragma unroll
    for (int j = 0; j < 2; ++j) *(bf16x8*)(&sA[asw[j]]) = pA[j];
#pragma unroll
    for (int j = 0; j < 4; ++j) *(bf16x8*)(&sB[bsw[j]]) = pB[j];
    __syncthreads();
    if (k0 + 64 < NH) {
#pragma unroll
      for (int j = 0; j < 2; ++j) pA[j] = *(const bf16x8*)(aptr[j] + k0 + 64);
#pragma unroll
      for (int j = 0; j < 4; ++j) pB[j] = *(const bf16x8*)(bptr[j] + k0 + 64);
    }
#pragma unroll
    for (int ks = 0; ks < 64; ks += 32) {
      bf16x8 af[2], bfr[4];
#pragma unroll
      for (int t = 0; t < 2; ++t)
        af[t] = *(const bf16x8*)(&sA[(wm + t * 16 + l15) * 64 + (((ks >> 3) + lq) ^ swzbase) * 8]);
#pragma unroll
      for (int t = 0; t < 4; ++t)
        bfr[t] = *(const bf16x8*)(&sB[(wn + t * 16 + l15) * 64 + (((ks >> 3) + lq) ^ swzbase) * 8]);
#pragma unroll
      for (int mt = 0; mt < 2; ++mt)
#pragma unroll
        for (int nt = 0; nt < 4; ++nt)
          acc[mt][nt] = __builtin_amdgcn_mfma_f32_16x16x32_bf16(af[mt], bfr[nt], acc[mt][nt], 0, 0, 0);
    }
    __syncthreads();
  }
#pragma unroll
  for (int mt = 0; mt < 2; ++mt) {
#pragma unroll
    for (int r = 0; r < 4; ++r) {
      int gr = bm + wm + mt * 16 + lq * 4 + r;
      if (gr < NN) {
#pragma unroll
        for (int nt = 0; nt < 4; ++nt) {
          int gc = wn + nt * 16 + l15;
          C[(size_t)gr * NL + gc] = f2bf(acc[mt][nt][r]);
        }
      }
    }
  }
}

// ---------------- SpMM (CSR row-gather), bf16 src, unroll-8/4/1, fused bias+relu ----------------
extern "C" __global__ __launch_bounds__(256) void k_spmm256(
    const int* __restrict__ rp, const int2* __restrict__ ep,
    const unsigned short* __restrict__ src, const float* __restrict__ bias,
    ushort4* __restrict__ out) {
  int row = blockIdx.x * 4 + (threadIdx.x >> 6);
  int lane = threadIdx.x & 63;
  if (row >= NN) return;
  int e0 = __builtin_amdgcn_readfirstlane(rp[row]);
  int e1 = __builtin_amdgcn_readfirstlane(rp[row + 1]);
  const ushort4* srcv = (const ushort4*)src;
  float4 acc = {0.f, 0.f, 0.f, 0.f};
  int e = e0;
  for (; e + 8 <= e1; e += 8) {
    int2 p[8]; ushort4 g[8];
#pragma unroll
    for (int j = 0; j < 8; ++j) p[j] = ep[e + j];
#pragma unroll
    for (int j = 0; j < 8; ++j) g[j] = srcv[(size_t)p[j].x * (NH / 4) + lane];
#pragma unroll
    for (int j = 0; j < 8; ++j) {
      float v = __int_as_float(p[j].y);
      acc.x = fmaf(v, bf2f(g[j].x), acc.x); acc.y = fmaf(v, bf2f(g[j].y), acc.y);
      acc.z = fmaf(v, bf2f(g[j].z), acc.z); acc.w = fmaf(v, bf2f(g[j].w), acc.w);
    }
  }
  for (; e + 4 <= e1; e += 4) {
    int2 p[4]; ushort4 g[4];
#pragma unroll
    for (int j = 0; j < 4; ++j) p[j] = ep[e + j];
#pragma unroll
    for (int j = 0; j < 4; ++j) g[j] = srcv[(size_t)p[j].x * (NH / 4) + lane];
#pragma unroll
    for (int j = 0; j < 4; ++j) {
      float v = __int_as_float(p[j].y);
      acc.x = fmaf(v, bf2f(g[j].x), acc.x); acc.y = fmaf(v, bf2f(g[j].y), acc.y);
      acc.z = fmaf(v, bf2f(g[j].z), acc.z); acc.w = fmaf(v, bf2f(g[j].w), acc.w);
    }
  }
  for (; e < e1; ++e) {
    int2 p = ep[e];
    float v = __int_as_float(p.y);
    ushort4 g = srcv[(size_t)p.x * (NH / 4) + lane];
    acc.x = fmaf(v, bf2f(g.x), acc.x); acc.y = fmaf(v, bf2f(g.y), acc.y);
    acc.z = fmaf(v, bf2f(g.z), acc.z); acc.w = fmaf(v, bf2f(g.w), acc.w);
  }
  float4 b = ((const float4*)bias)[lane];
  ushort4 o;
  o.x = f2bf(fmaxf(acc.x + b.x, 0.f));
  o.y = f2bf(fmaxf(acc.y + b.y, 0.f));
  o.z = f2bf(fmaxf(acc.z + b.z, 0.f));
  o.w = f2bf(fmaxf(acc.w + b.w, 0.f));
  out[(size_t)row * (NH / 4) + lane] = o;
}

extern "C" __global__ __launch_bounds__(256) void k_spmm128(
    const int* __restrict__ rp, const int2* __restrict__ ep,
    const unsigned short* __restrict__ src, const float* __restrict__ bias,
    float2* __restrict__ out) {
  int row = blockIdx.x * 4 + (threadIdx.x >> 6);
  int lane = threadIdx.x & 63;
  if (row >= NN) return;
  int e0 = __builtin_amdgcn_readfirstlane(rp[row]);
  int e1 = __builtin_amdgcn_readfirstlane(rp[row + 1]);
  const ushort2* srcv = (const ushort2*)src;
  float2 acc = {0.f, 0.f};
  int e = e0;
  for (; e + 8 <= e1; e += 8) {
    int2 p[8]; ushort2 g[8];
#pragma unroll
    for (int j = 0; j < 8; ++j) p[j] = ep[e + j];
#pragma unroll
    for (int j = 0; j < 8; ++j) g[j] = srcv[(size_t)p[j].x * (NL / 2) + lane];
#pragma unroll
    for (int j = 0; j < 8; ++j) {
      float v = __int_as_float(p[j].y);
      acc.x = fmaf(v, bf2f(g[j].x), acc.x); acc.y = fmaf(v, bf2f(g[j].y), acc.y);
    }
  }
  for (; e + 4 <= e1; e += 4) {
    int2 p[4]; ushort2 g[4];
#pragma unroll
    for (int j = 0; j < 4; ++j) p[j] = ep[e + j];
#pragma unroll
    for (int j = 0; j < 4; ++j) g[j] = srcv[(size_t)p[j].x * (NL / 2) + lane];
#pragma unroll
    for (int j = 0; j < 4; ++j) {
      float v = __int_as_float(p[j].y);
      acc.x = fmaf(v, bf2f(g[j].x), acc.x); acc.y = fmaf(v, bf2f(g[j].y), acc.y);
    }
  }
  for (; e < e1; ++e) {
    int2 p = ep[e];
    float v = __int_as_float(p.y);
    ushort2 g = srcv[(size_t)p.x * (NL / 2) + lane];
    acc.x = fmaf(v, bf2f(g.x), acc.x); acc.y = fmaf(v, bf2f(g.y), acc.y);
  }
  float2 b = ((const float2*)bias)[lane];
  float2 o;
  o.x = fmaxf(acc.x + b.x, 0.f);
  o.y = fmaxf(acc.y + b.y, 0.f);
  out[(size_t)row * (NL / 2) + lane] = o;
}

// ---------------- launch ----------------
extern "C" void kernel_launch(void* const* d_in, const int* in_sizes, int n_in,
                              void* d_out, int out_size, void* d_ws, size_t ws_size,
                              hipStream_t stream) {
  const float* x   = (const float*)d_in[0];
  const int* erow  = (const int*)d_in[1];
  const int* ecol  = (const int*)d_in[2];
  const float* ev  = (const float*)d_in[3];
  const float* W1  = (const float*)d_in[4];
  const float* b1  = (const float*)d_in[5];
  const float* W2  = (const float*)d_in[6];
  const float* b2  = (const float*)d_in[7];

  char* ws = (char*)d_ws;
  unsigned short* xwb = (unsigned short*)(ws + 0);           // 25,600,000 (x@W1 bf16)
  unsigned short* hbf = (unsigned short*)(ws + 25600000);    // 25,600,000 (h bf16)
  unsigned short* hwb = (unsigned short*)(ws + 51200000);    // 12,800,000 (h@W2 bf16)
  unsigned short* w1t = (unsigned short*)(ws + 64000000);    // 262,144
  unsigned short* w2t = (unsigned short*)(ws + 64262144);    // 65,536
  int* rp    = (int*)(ws + 64327680);                        // 200,704
  int* cur   = (int*)(ws + 64528384);                        // 200,704
  int* cnt   = (int*)(ws + 64729088);                        // 200,704
  int* bsum  = (int*)(ws + 64929792);                        // 1,024
  int* bpre  = (int*)(ws + 64930816);                        // 1,024
  int2* ep   = (int2*)(ws + 64931840);                       // 6,400,000

  // CSR build
  hipMemsetAsync(cnt, 0, NN * sizeof(int), stream);
  k_hist<<<NE / 256, 256, 0, stream>>>(erow, cnt, NE);
  k_blocksum<<<NB, 256, 0, stream>>>(cnt, bsum, NN);
  k_scansums<<<1, 256, 0, stream>>>(bsum, bpre, rp, NB, NN);
  k_scanfin<<<NB, 256, 0, stream>>>(cnt, bpre, rp, cur, NN);
  k_scatter<<<NE / 256, 256, 0, stream>>>(erow, ecol, ev, cur, ep, NE);

  // layer 1
  k_transcast<<<NF, NH, 0, stream>>>(W1, w1t, NF, NH);
  k_gemm1<<<dim3((NN + 127) / 128, NH / 128), 256, 0, stream>>>(x, w1t, xwb);
  k_spmm256<<<NN / 4, 256, 0, stream>>>(rp, ep, xwb, b1, (ushort4*)hbf);

  // layer 2
  k_transcast<<<NH, NL, 0, stream>>>(W2, w2t, NH, NL);
  k_gemm2<<<(NN + 63) / 64, 256, 0, stream>>>(hbf, w2t, hwb);
  k_spmm128<<<NN / 4, 256, 0, stream>>>(rp, ep, hwb, b2, (float2*)d_out);
}